// Round 5
// baseline (367.253 us; speedup 1.0000x reference)
//
#include <hip/hip_runtime.h>
#include <hip/hip_bf16.h>

#define SLOPE 0.2f
#define DH 256
#define DE 128

typedef __bf16 bf16_t;
typedef bf16_t bf16x8 __attribute__((ext_vector_type(8)));
typedef bf16_t bf16x4 __attribute__((ext_vector_type(4)));
typedef float f32x4 __attribute__((ext_vector_type(4)));

__device__ __forceinline__ float lrelu(float x) { return x > 0.f ? x : SLOPE * x; }

// ---------------------------------------------------------------------------
// Cast + transpose weights to bf16: wT[n][k] = wW[k][n]  (256x256)
//                                   ewT[n][k] = ewW[k][n] (256x128)
// ---------------------------------------------------------------------------
__global__ void prep_weights(const float* __restrict__ wW, const float* __restrict__ ewW,
                             bf16_t* __restrict__ wT, bf16_t* __restrict__ ewT) {
    int n = blockIdx.x;   // 0..255 (output col of original)
    int k = threadIdx.x;  // 0..255
    wT[n * 256 + k] = (bf16_t)wW[k * 256 + n];
    if (k < 128) ewT[n * 128 + k] = (bf16_t)ewW[k * 256 + n];
}

// ---------------------------------------------------------------------------
// Node projection: h = lrelu(nf @ wW + wb)  [N,256], bf16 out
// epilogue also computes s1 = h . aW[0:256], s2 = h . aW[256:512] (fp32)
// ---------------------------------------------------------------------------
__global__ __launch_bounds__(256) void node_proj(const float* __restrict__ nf,
                                                 const bf16_t* __restrict__ wT,
                                                 const float* __restrict__ wb,
                                                 const float* __restrict__ aW,
                                                 bf16_t* __restrict__ h,
                                                 float* __restrict__ s1,
                                                 float* __restrict__ s2, int N) {
    __shared__ bf16_t A[64][264];
    __shared__ float p1[4][64];
    __shared__ float p2[4][64];

    const int tid = threadIdx.x;
    const int wave = tid >> 6, lane = tid & 63;
    const int q = lane >> 4, l = lane & 15;
    const int m0 = blockIdx.x * 64;

    for (int i = tid; i < 64 * 64; i += 256) {
        int r = i >> 6;
        int c4 = (i & 63) * 4;
        int row = m0 + r;
        if (row >= N) row = N - 1;
        const float4 v = *(const float4*)(nf + (size_t)row * 256 + c4);
        bf16_t* dst = &A[r][c4];
        dst[0] = (bf16_t)v.x; dst[1] = (bf16_t)v.y; dst[2] = (bf16_t)v.z; dst[3] = (bf16_t)v.w;
    }
    __syncthreads();

    f32x4 acc[4][4];
    for (int rt = 0; rt < 4; rt++)
        for (int ct = 0; ct < 4; ct++)
            acc[rt][ct] = (f32x4){0.f, 0.f, 0.f, 0.f};

    for (int kc = 0; kc < 8; kc++) {
        bf16x8 bf[4];
        for (int ct = 0; ct < 4; ct++) {
            int n = wave * 64 + ct * 16 + l;
            bf[ct] = *(const bf16x8*)(wT + (size_t)n * 256 + kc * 32 + q * 8);
        }
        bf16x8 af[4];
        for (int rt = 0; rt < 4; rt++)
            af[rt] = *(const bf16x8*)(&A[rt * 16 + l][kc * 32 + q * 8]);
        for (int rt = 0; rt < 4; rt++)
            for (int ct = 0; ct < 4; ct++)
                acc[rt][ct] = __builtin_amdgcn_mfma_f32_16x16x32_bf16(af[rt], bf[ct], acc[rt][ct], 0, 0, 0);
    }

    float bias[4], w1[4], w2[4];
    for (int ct = 0; ct < 4; ct++) {
        int n = wave * 64 + ct * 16 + l;
        bias[ct] = wb[n];
        w1[ct] = aW[n];
        w2[ct] = aW[256 + n];
    }
    for (int rt = 0; rt < 4; rt++) {
        float rs1[4] = {0.f, 0.f, 0.f, 0.f};
        float rs2[4] = {0.f, 0.f, 0.f, 0.f};
        for (int ct = 0; ct < 4; ct++) {
            int col = wave * 64 + ct * 16 + l;
            for (int r = 0; r < 4; r++) {
                float p = lrelu(acc[rt][ct][r] + bias[ct]);
                int row = m0 + rt * 16 + q * 4 + r;
                if (row < N) h[(size_t)row * 256 + col] = (bf16_t)p;
                rs1[r] += p * w1[ct];
                rs2[r] += p * w2[ct];
            }
        }
        for (int off = 1; off < 16; off <<= 1) {
            for (int r = 0; r < 4; r++) {
                rs1[r] += __shfl_xor(rs1[r], off, 64);
                rs2[r] += __shfl_xor(rs2[r], off, 64);
            }
        }
        if (l == 0) {
            for (int r = 0; r < 4; r++) {
                p1[wave][rt * 16 + q * 4 + r] = rs1[r];
                p2[wave][rt * 16 + q * 4 + r] = rs2[r];
            }
        }
    }
    __syncthreads();
    if (tid < 64 && m0 + tid < N) {
        s1[m0 + tid] = p1[0][tid] + p1[1][tid] + p1[2][tid] + p1[3][tid];
        s2[m0 + tid] = p2[0][tid] + p2[1][tid] + p2[2][tid] + p2[3][tid];
    }
}

// ---------------------------------------------------------------------------
// Edge projection v5: s3[e] = lrelu(ef[e] @ ewW + ewb) . aW[512:768] + a_b
// B (ewT) resident in LDS per block. Waves grid-stride over 32-edge chunks;
// each LDS B-fragment read feeds TWO MFMAs (edge groups 0-15 / 16-31), halving
// LDS traffic to 2 KB/edge -> HBM-bound. Quarter-passes over ct keep acc at
// 32 VGPRs (target total <=128 so LDS's 2 blocks/CU limit stays binding).
// ---------------------------------------------------------------------------
__global__ __launch_bounds__(512) void edge_proj(const float* __restrict__ ef,
                                                 const bf16_t* __restrict__ ewT,
                                                 const float* __restrict__ eb,
                                                 const float* __restrict__ aW,
                                                 const float* __restrict__ ab,
                                                 float* __restrict__ s3, int E,
                                                 int grid_blocks) {
    __shared__ bf16_t B[256][136];
    __shared__ float2 EW[256];

    const int tid = threadIdx.x;
    const int wave = tid >> 6, lane = tid & 63;
    const int q = lane >> 4, l = lane & 15;

    {
        int col = tid >> 1, half = tid & 1;
        const bf16x8* src = (const bf16x8*)(ewT + (size_t)col * 128 + half * 64);
        bf16_t* dst = &B[col][half * 64];
#pragma unroll
        for (int i = 0; i < 8; i++)
            *(bf16x8*)(dst + i * 8) = src[i];
    }
    if (tid < 256) EW[tid] = make_float2(eb[tid], aW[512 + tid]);
    const float ab0 = ab[0];
    __syncthreads();

    const int nchunks = (E + 31) >> 5;
    const int wstride = grid_blocks * 8;

    for (int c = blockIdx.x * 8 + wave; c < nchunks; c += wstride) {
        const int e0 = c * 32;

        // load + convert A for both 16-edge groups
        bf16x8 af0[4], af1[4];
        {
            int row = e0 + l;
            if (row >= E) row = E - 1;
            const float* ar = ef + (size_t)row * 128 + q * 8;
            f32x4 a0[4], a1[4];
#pragma unroll
            for (int kc = 0; kc < 4; kc++) {
                a0[kc] = *(const f32x4*)(ar + kc * 32);
                a1[kc] = *(const f32x4*)(ar + kc * 32 + 4);
            }
#pragma unroll
            for (int kc = 0; kc < 4; kc++) {
                af0[kc][0] = (bf16_t)a0[kc][0]; af0[kc][1] = (bf16_t)a0[kc][1];
                af0[kc][2] = (bf16_t)a0[kc][2]; af0[kc][3] = (bf16_t)a0[kc][3];
                af0[kc][4] = (bf16_t)a1[kc][0]; af0[kc][5] = (bf16_t)a1[kc][1];
                af0[kc][6] = (bf16_t)a1[kc][2]; af0[kc][7] = (bf16_t)a1[kc][3];
            }
            int row2 = e0 + 16 + l;
            if (row2 >= E) row2 = E - 1;
            const float* ar2 = ef + (size_t)row2 * 128 + q * 8;
#pragma unroll
            for (int kc = 0; kc < 4; kc++) {
                a0[kc] = *(const f32x4*)(ar2 + kc * 32);
                a1[kc] = *(const f32x4*)(ar2 + kc * 32 + 4);
            }
#pragma unroll
            for (int kc = 0; kc < 4; kc++) {
                af1[kc][0] = (bf16_t)a0[kc][0]; af1[kc][1] = (bf16_t)a0[kc][1];
                af1[kc][2] = (bf16_t)a0[kc][2]; af1[kc][3] = (bf16_t)a0[kc][3];
                af1[kc][4] = (bf16_t)a1[kc][0]; af1[kc][5] = (bf16_t)a1[kc][1];
                af1[kc][6] = (bf16_t)a1[kc][2]; af1[kc][7] = (bf16_t)a1[kc][3];
            }
        }

        float rs0[4] = {0.f, 0.f, 0.f, 0.f};   // group0: edges e0 + q*4 + r
        float rs1[4] = {0.f, 0.f, 0.f, 0.f};   // group1: edges e0 + 16 + q*4 + r
#pragma unroll 1
        for (int qt = 0; qt < 4; qt++) {
            f32x4 acc0[4], acc1[4];
#pragma unroll
            for (int t = 0; t < 4; t++) {
                acc0[t] = (f32x4){0.f, 0.f, 0.f, 0.f};
                acc1[t] = (f32x4){0.f, 0.f, 0.f, 0.f};
            }
#pragma unroll
            for (int kc = 0; kc < 4; kc++) {
#pragma unroll
                for (int t = 0; t < 4; t++) {
                    int ct = qt * 4 + t;
                    bf16x8 bf = *(const bf16x8*)(&B[ct * 16 + l][kc * 32 + q * 8]);
                    acc0[t] = __builtin_amdgcn_mfma_f32_16x16x32_bf16(af0[kc], bf, acc0[t], 0, 0, 0);
                    acc1[t] = __builtin_amdgcn_mfma_f32_16x16x32_bf16(af1[kc], bf, acc1[t], 0, 0, 0);
                }
            }
#pragma unroll
            for (int t = 0; t < 4; t++) {
                int ct = qt * 4 + t;
                float2 bw = EW[ct * 16 + l];
#pragma unroll
                for (int r = 0; r < 4; r++) {
                    rs0[r] += lrelu(acc0[t][r] + bw.x) * bw.y;
                    rs1[r] += lrelu(acc1[t][r] + bw.x) * bw.y;
                }
            }
        }
#pragma unroll
        for (int off = 1; off < 16; off <<= 1) {
#pragma unroll
            for (int r = 0; r < 4; r++) {
                rs0[r] += __shfl_xor(rs0[r], off, 64);
                rs1[r] += __shfl_xor(rs1[r], off, 64);
            }
        }
        if (l == 0) {
#pragma unroll
            for (int r = 0; r < 4; r++) {
                int ea = e0 + q * 4 + r;
                if (ea < E) s3[ea] = rs0[r] + ab0;
                int eb2 = e0 + 16 + q * 4 + r;
                if (eb2 < E) s3[eb2] = rs1[r] + ab0;
            }
        }
    }
}

// ---------------------------------------------------------------------------
// CSR build
// ---------------------------------------------------------------------------
__global__ void count_edges(const int* __restrict__ tgt, int* __restrict__ counts, int E) {
    int e = blockIdx.x * blockDim.x + threadIdx.x;
    if (e < E) atomicAdd(&counts[tgt[e]], 1);
}

__global__ __launch_bounds__(256) void scan_kernel(const int* __restrict__ counts,
                                                   int* __restrict__ rowstart, int N) {
    __shared__ int sdata[256];
    int t = threadIdx.x;
    int CH = (N + 255) >> 8;
    int i0 = t * CH;
    int sum = 0;
    for (int i = 0; i < CH; i++) {
        int idx = i0 + i;
        if (idx < N) sum += counts[idx];
    }
    sdata[t] = sum;
    __syncthreads();
    for (int off = 1; off < 256; off <<= 1) {
        int v = (t >= off) ? sdata[t - off] : 0;
        __syncthreads();
        sdata[t] += v;
        __syncthreads();
    }
    int run = sdata[t] - sum;
    for (int i = 0; i < CH; i++) {
        int idx = i0 + i;
        if (idx < N) {
            rowstart[idx] = run;
            run += counts[idx];
        }
    }
    if (t == 255) rowstart[N] = sdata[255];
}

// fill CSR slot AND compute the attention logit in one pass:
// pairs[rowstart[t]+p] = { j (as int bits), s1[t]+s2[j]+s3[e] }
__global__ void fill_edges(const int* __restrict__ tgt, const int* __restrict__ nbr,
                           const int* __restrict__ rowstart, int* __restrict__ cursor,
                           const float* __restrict__ s1, const float* __restrict__ s2,
                           const float* __restrict__ s3, float2* __restrict__ pairs, int E) {
    int e = blockIdx.x * blockDim.x + threadIdx.x;
    if (e < E) {
        int t = tgt[e];
        int j = nbr[e];
        float logit = s1[t] + s2[j] + s3[e];
        int p = atomicAdd(&cursor[t], 1);
        float2 pr;
        pr.x = __int_as_float(j);
        pr.y = logit;
        pairs[rowstart[t] + p] = pr;
    }
}

// ---------------------------------------------------------------------------
// Aggregate v4: one WAVE per node. Online softmax (single fused max+sum pass)
// then weighted h-gather. Zero LDS, zero barriers, no degree cap.
// ---------------------------------------------------------------------------
__global__ __launch_bounds__(256) void aggregate(const int* __restrict__ rowstart,
                                                 const float2* __restrict__ pairs,
                                                 const bf16_t* __restrict__ h,
                                                 float* __restrict__ out, int N) {
    const int wave = threadIdx.x >> 6, lane = threadIdx.x & 63;
    const int n = blockIdx.x * 4 + wave;
    if (n >= N) return;

    int rs = __builtin_amdgcn_readfirstlane(rowstart[n]);
    int deg = __builtin_amdgcn_readfirstlane(rowstart[n + 1]) - rs;
    const float2* pp = pairs + rs;

    // fused pass: online (max, exp-sum) per lane
    float m = -1e30f, s = 0.f;
    for (int i = lane; i < deg; i += 64) {
        float x = pp[i].y;
        float mn = fmaxf(m, x);
        s = s * expf(m - mn) + expf(x - mn);
        m = mn;
    }
    // lane merge
#pragma unroll
    for (int off = 32; off > 0; off >>= 1) {
        float mo = __shfl_xor(m, off, 64);
        float so = __shfl_xor(s, off, 64);
        float mn = fmaxf(m, mo);
        s = s * expf(m - mn) + so * expf(mo - mn);
        m = mn;
    }
    const float inv = (deg > 0 && s > 0.f) ? 1.0f / s : 0.f;

    // weighted gather: out[n][lane*4..+4) = sum_i exp(y_i-m) * h[j_i][lane*4..+4)
    f32x4 acc = (f32x4){0.f, 0.f, 0.f, 0.f};
    const bf16_t* hf = h + lane * 4;
#pragma unroll 4
    for (int i = 0; i < deg; i++) {
        float2 pr = pp[i];                       // wave-broadcast load
        float a = expf(pr.y - m);
        int j = __float_as_int(pr.x);
        bf16x4 v = *(const bf16x4*)(hf + (size_t)j * 256);
        acc[0] += a * (float)v[0];
        acc[1] += a * (float)v[1];
        acc[2] += a * (float)v[2];
        acc[3] += a * (float)v[3];
    }
    float4 o;
    o.x = lrelu(acc[0] * inv);
    o.y = lrelu(acc[1] * inv);
    o.z = lrelu(acc[2] * inv);
    o.w = lrelu(acc[3] * inv);
    *(float4*)(out + (size_t)n * 256 + lane * 4) = o;
}

// ---------------------------------------------------------------------------
extern "C" void kernel_launch(void* const* d_in, const int* in_sizes, int n_in,
                              void* d_out, int out_size, void* d_ws, size_t ws_size,
                              hipStream_t stream) {
    const float* nf  = (const float*)d_in[0];
    const float* ef  = (const float*)d_in[1];
    const int*  eidx = (const int*)d_in[2];
    const float* wW  = (const float*)d_in[3];
    const float* wb  = (const float*)d_in[4];
    const float* ewW = (const float*)d_in[5];
    const float* ewb = (const float*)d_in[6];
    const float* aW  = (const float*)d_in[7];
    const float* ab  = (const float*)d_in[8];
    float* out = (float*)d_out;

    const int N = in_sizes[0] / DH;   // 10000
    const int E = in_sizes[1] / DE;   // 320000
    const int* tgt = eidx;
    const int* nbr = eidx + E;

    char* ws = (char*)d_ws;
    size_t off = 0;
    auto alloc = [&](size_t bytes) -> void* {
        void* p = ws + off;
        off += (bytes + 255) & ~(size_t)255;
        return p;
    };
    bf16_t* wT      = (bf16_t*)alloc((size_t)256 * 256 * 2);
    bf16_t* ewT     = (bf16_t*)alloc((size_t)256 * 128 * 2);
    bf16_t* h       = (bf16_t*)alloc((size_t)N * 256 * 2);
    float*  s1      = (float*)alloc((size_t)N * 4);
    float*  s2      = (float*)alloc((size_t)N * 4);
    float*  s3      = (float*)alloc((size_t)E * 4);
    int*    counts  = (int*)alloc((size_t)N * 4);
    int*    cursor  = (int*)alloc((size_t)N * 4);
    int*    rowstart= (int*)alloc((size_t)(N + 1) * 4);
    float2* pairs   = (float2*)alloc((size_t)E * 8);

    prep_weights<<<256, 256, 0, stream>>>(wW, ewW, wT, ewT);
    node_proj<<<(N + 63) / 64, 256, 0, stream>>>(nf, wT, wb, aW, h, s1, s2, N);

    const int EP_BLOCKS = 512;
    edge_proj<<<EP_BLOCKS, 512, 0, stream>>>(ef, ewT, ewb, aW, ab, s3, E, EP_BLOCKS);

    size_t zspan = (size_t)((char*)cursor + (size_t)N * 4 - (char*)counts);
    hipMemsetAsync(counts, 0, zspan, stream);
    count_edges<<<(E + 255) / 256, 256, 0, stream>>>(tgt, counts, E);
    scan_kernel<<<1, 256, 0, stream>>>(counts, rowstart, N);
    fill_edges<<<(E + 255) / 256, 256, 0, stream>>>(tgt, nbr, rowstart, cursor, s1, s2, s3, pairs, E);
    aggregate<<<(N + 3) / 4, 256, 0, stream>>>(rowstart, pairs, h, out, N);
}